// Round 6
// baseline (167.006 us; speedup 1.0000x reference)
//
#include <hip/hip_runtime.h>
#include <hip/hip_bf16.h>
#include <math.h>

#define D      256
#define N2     8192
#define NHALF  4096

typedef __bf16 bf16x8_t __attribute__((ext_vector_type(8)));
typedef __bf16 bf16x4_t __attribute__((ext_vector_type(4)));
typedef float  f32x4_t  __attribute__((ext_vector_type(4)));

// exp(2s) = 2^(2*log2e*s); prescale both GEMM operands by sqrt(2*log2e) so the
// MFMA accumulator is directly the exp2 argument.
#define SCL 1.6986437f   // sqrt(2 * 1.44269504)

// ---------------- kernel 1: fused normalize(+prescale) + positives + zeroing ------
__global__ __launch_bounds__(256) void prep_kernel(const float* __restrict__ a,
                                                   const float* __restrict__ b,
                                                   __bf16* __restrict__ zb,
                                                   float* __restrict__ g_pos,
                                                   float* __restrict__ g_denom,
                                                   int* __restrict__ d_done) {
    const int tid = threadIdx.x;
    const int gt  = blockIdx.x * 256 + tid;
    if (gt < N2) g_denom[gt] = 0.0f;
    if (gt == 0) d_done[0] = 0;

    const int w = blockIdx.x * 4 + (tid >> 6);  // pair row in [0, NHALF)
    const int l = tid & 63;
    float4 x = ((const float4*)(a + (size_t)w * D))[l];
    float4 y = ((const float4*)(b + (size_t)w * D))[l];
    float sxx = x.x * x.x + x.y * x.y + x.z * x.z + x.w * x.w;
    float syy = y.x * y.x + y.y * y.y + y.z * y.z + y.w * y.w;
    float sxy = x.x * y.x + x.y * y.y + x.z * y.z + x.w * y.w;
    #pragma unroll
    for (int off = 32; off; off >>= 1) {
        sxx += __shfl_xor(sxx, off, 64);
        syy += __shfl_xor(syy, off, 64);
        sxy += __shfl_xor(sxy, off, 64);
    }
    const float rx = 1.0f / fmaxf(sqrtf(sxx), 1e-8f);
    const float ry = 1.0f / fmaxf(sqrtf(syy), 1e-8f);
    const float sx = rx * SCL;
    const float sy = ry * SCL;

    bf16x4_t ox, oy;
    ox[0] = (__bf16)(x.x * sx); ox[1] = (__bf16)(x.y * sx);
    ox[2] = (__bf16)(x.z * sx); ox[3] = (__bf16)(x.w * sx);
    oy[0] = (__bf16)(y.x * sy); oy[1] = (__bf16)(y.y * sy);
    oy[2] = (__bf16)(y.z * sy); oy[3] = (__bf16)(y.w * sy);
    *(bf16x4_t*)(zb + (size_t)w * D + l * 4)           = ox;
    *(bf16x4_t*)(zb + (size_t)(w + NHALF) * D + l * 4) = oy;

    if (l == 0) {
        const float p = sxy * rx * ry;   // exact fp32 positive similarity
        g_pos[w]         = p;
        g_pos[w + NHALF] = p;
    }
}

// ---------------- kernel 2: full-matrix sim, reg-resident A, row-sum-only epilogue -
// Block = (col-chunkgroup cg, 64-row band b): blockIdx.x = cg*128 + b (same-XCD
// blocks share a 2048-col group -> L2 locality). 4 waves split the group into 512-col
// chunks. Wave: A-frags 64 rows x K=256 resident (128 VGPRs); 32 strips of 16 cols,
// B double-buffered in registers (constant-indexed arrays, no pointer indirection).
// Row sums accumulate in registers across all strips; ONE shuffle-reduce + 4 atomic
// instrs per wave. No symmetry -> no column sums -> no per-strip cross-lane work.
// Last block (device-scope counter) computes the final scalar loss.
__global__ __launch_bounds__(256, 2) void sim_kernel(const __bf16* __restrict__ zb,
                                                     float* __restrict__ g_denom,
                                                     const float* __restrict__ g_pos,
                                                     int* __restrict__ d_done,
                                                     float* __restrict__ out) {
    const int tid    = threadIdx.x;
    const int w      = tid >> 6;
    const int l      = tid & 63;
    const int lane15 = l & 15;
    const int quad   = l >> 4;

    const int band = blockIdx.x & 127;          // 0..127
    const int cg   = blockIdx.x >> 7;           // 0..3
    const int r0   = band * 64;
    const int c0   = (cg * 4 + w) * 512;        // this wave's 512 cols

    // A fragments: 64 rows x K=256, register-resident for the whole kernel
    bf16x8_t af[4][8];
    {
        const __bf16* abase = zb + (size_t)(r0 + lane15) * D + quad * 8;
        #pragma unroll
        for (int mi = 0; mi < 4; ++mi)
            #pragma unroll
            for (int kc = 0; kc < 8; ++kc)
                af[mi][kc] = *(const bf16x8_t*)(abase + (size_t)mi * 16 * D + kc * 32);
    }

    float rs[4] = {0.f, 0.f, 0.f, 0.f};
    bf16x8_t b0[8], b1[8];

#define LOADB(S, BB)                                                              \
    {                                                                             \
        const __bf16* bbase = zb + (size_t)(c0 + (S) * 16 + lane15) * D + quad * 8; \
        _Pragma("unroll")                                                         \
        for (int kc = 0; kc < 8; ++kc)                                            \
            BB[kc] = *(const bf16x8_t*)(bbase + kc * 32);                         \
    }

#define COMPUTE(S, BB)                                                            \
    {                                                                             \
        f32x4_t acc[4] = {};                                                      \
        _Pragma("unroll")                                                         \
        for (int kc = 0; kc < 8; ++kc)                                            \
            _Pragma("unroll")                                                     \
            for (int mi = 0; mi < 4; ++mi)                                        \
                acc[mi] = __builtin_amdgcn_mfma_f32_16x16x32_bf16(                \
                    BB[kc], af[mi][kc], acc[mi], 0, 0, 0);                        \
        const int cs = c0 + (S) * 16;                                             \
        if (cs >= r0 && cs < r0 + 64) { /* strip crosses the diagonal */          \
            _Pragma("unroll")                                                     \
            for (int mi = 0; mi < 4; ++mi) {                                      \
                const int row = r0 + 16 * mi + lane15;                            \
                _Pragma("unroll")                                                 \
                for (int t = 0; t < 4; ++t) {                                     \
                    const int n = cs + quad * 4 + t;                              \
                    const float e = exp2f(acc[mi][t]);                            \
                    rs[mi] += (n == row) ? 0.0f : e;                              \
                }                                                                 \
            }                                                                     \
        } else {                                                                  \
            _Pragma("unroll")                                                     \
            for (int mi = 0; mi < 4; ++mi)                                        \
                _Pragma("unroll")                                                 \
                for (int t = 0; t < 4; ++t)                                       \
                    rs[mi] += exp2f(acc[mi][t]);                                  \
        }                                                                         \
    }

    LOADB(0, b0);
    #pragma unroll 1
    for (int s = 0; s < 32; s += 2) {
        LOADB(s + 1, b1);
        COMPUTE(s, b0);
        if (s + 2 < 32) LOADB(s + 2, b0);
        COMPUTE(s + 1, b1);
    }
#undef LOADB
#undef COMPUTE

    // row sums: reduce the 4 quad groups, then 4 atomic instrs per wave (lanes 0-15)
    #pragma unroll
    for (int mi = 0; mi < 4; ++mi) {
        rs[mi] += __shfl_xor(rs[mi], 16, 64);
        rs[mi] += __shfl_xor(rs[mi], 32, 64);
    }
    if (l < 16) {
        #pragma unroll
        for (int mi = 0; mi < 4; ++mi)
            atomicAdd(&g_denom[r0 + 16 * mi + l], rs[mi]);
    }

    // ---- folded finalize: last block to finish reduces 8192 rows -> scalar ----
    __shared__ int  slast;
    __shared__ float sw[4];
    __threadfence();                              // release our denom adds
    if (tid == 0) slast = (atomicAdd(d_done, 1) == (int)gridDim.x - 1);
    __syncthreads();
    if (slast) {
        __threadfence();                          // acquire all denom adds
        float local = 0.0f;
        for (int k = tid; k < N2; k += 256)
            local += logf(g_denom[k]) - 2.0f * g_pos[k];
        #pragma unroll
        for (int off = 32; off; off >>= 1) local += __shfl_xor(local, off, 64);
        if ((tid & 63) == 0) sw[tid >> 6] = local;
        __syncthreads();
        if (tid == 0) out[0] = (sw[0] + sw[1] + sw[2] + sw[3]) / (float)N2;
    }
}

extern "C" void kernel_launch(void* const* d_in, const int* in_sizes, int n_in,
                              void* d_out, int out_size, void* d_ws, size_t ws_size,
                              hipStream_t stream) {
    const float* emb_i = (const float*)d_in[0];
    const float* emb_j = (const float*)d_in[1];

    __bf16* zb      = (__bf16*)d_ws;                                 // 4 MB
    float*  g_denom = (float*)((char*)d_ws + (size_t)N2 * D * 2);    // 8192 fp32
    float*  g_pos   = g_denom + N2;                                  // 8192 fp32
    int*    d_done  = (int*)(g_pos + N2);                            // 1 int
    float*  out     = (float*)d_out;

    prep_kernel<<<NHALF / 4, 256, 0, stream>>>(emb_i, emb_j, zb, g_pos, g_denom, d_done);
    sim_kernel<<<512, 256, 0, stream>>>(zb, g_denom, g_pos, d_done, out);
}